// Round 12
// baseline (132.275 us; speedup 1.0000x reference)
//
#include <hip/hip_runtime.h>
#include <hip/hip_bf16.h>

using u16 = unsigned short;
typedef __bf16 bf16x8 __attribute__((ext_vector_type(8)));
typedef float f32x4 __attribute__((ext_vector_type(4)));

#define N_B   16
#define L_S   512
#define D_F   256
#define T_MEL 4096
#define M_TOT (N_B * L_S)
#define OUT_ELEMS ((size_t)N_B * T_MEL * D_F)   // fp32 elems
#define H1_ELEMS  ((size_t)M_TOT * D_F)         // bf16 elems
#define WP_ELEMS  (24 * 8192)                   // packed weight elems per conv
#define TBLK 128

__device__ __forceinline__ u16 f2bf(float f) {
  __hip_bfloat16 h = __float2bfloat16(f);
  return *(u16*)&h;
}

__device__ __forceinline__ bf16x8 pack8(float4 v0, float4 v1) {
  union { bf16x8 h; u16 u[8]; } r;
  r.u[0] = f2bf(v0.x); r.u[1] = f2bf(v0.y); r.u[2] = f2bf(v0.z); r.u[3] = f2bf(v0.w);
  r.u[4] = f2bf(v1.x); r.u[5] = f2bf(v1.y); r.u[6] = f2bf(v1.z); r.u[7] = f2bf(v1.w);
  return r.h;
}

// ---------------------------------------------------------------------------
// Weight pack: wp[s][f][ki] = w[f][(s&7)*32+ki][s>>3]  (proven indexing).
// ---------------------------------------------------------------------------
__global__ __launch_bounds__(256)
void pack_kernel(const float* __restrict__ w1, const float* __restrict__ w2,
                 u16* __restrict__ wp1, u16* __restrict__ wp2) {
  int o   = (int)blockIdx.x * 256 + (int)threadIdx.x;   // 0..196607
  int s   = o >> 13;
  int rem = o & 8191;
  int f   = rem >> 5;
  int ki  = rem & 31;
  int d   = ((s & 7) << 5) + ki;
  int tap = s >> 3;
  int src = f * 768 + d * 3 + tap;
  wp1[o] = f2bf(w1[src]);
  wp2[o] = f2bf(w2[src]);
}

// ---------------------------------------------------------------------------
// 512-thread LR body (proven R6/R7): 256 lr-blocks, 256 T-rows each.
// ---------------------------------------------------------------------------
__device__ __forceinline__ void lr_body512(
    const int lrblk, const int t,
    const float* __restrict__ X, const int* __restrict__ tgt,
    float* __restrict__ out, int* sc, int* sidx)
{
  const int n  = lrblk >> 4;
  const int t0 = (lrblk & 15) * 256;

  sc[t] = tgt[n * L_S + t];
  __syncthreads();
  for (int off = 1; off < L_S; off <<= 1) {
    int v = (t >= off) ? sc[t - off] : 0;
    __syncthreads();
    sc[t] += v;
    __syncthreads();
  }
  const int total = sc[L_S - 1];
  if (t < 256) {
    int tt = t0 + t;
    int lo = 0, hi = L_S;
    while (lo < hi) {
      int mid = (lo + hi) >> 1;
      if (sc[mid] <= tt) lo = mid + 1; else hi = mid;
    }
    sidx[t] = (tt < total) ? lo : -1;
  }
  __syncthreads();

  #pragma unroll
  for (int i = 0; i < 32; i++) {
    int u   = t + i * 512;
    int dg  = u & 63;
    int tr  = u >> 6;
    int idx = sidx[tr];
    float4 v = make_float4(0.f, 0.f, 0.f, 0.f);
    if (idx >= 0)
      v = *(const float4*)(X + (((size_t)(n * L_S + idx)) << 8) + dg * 4);
    *(float4*)(out + (((size_t)(n * T_MEL + t0 + tr)) << 8) + dg * 4) = v;
  }
}

// ---------------------------------------------------------------------------
// FUSED conv1 -> conv2 (round 12). Blocks 0..255: per block, conv1 is
// computed for 64 rows (4 groups of 16: m0-16..m0+48) so the block owns the
// halo rows (m0-1, m0+32) itself -- MFMA is 2% util, recompute is free, and
// the extra row-groups ride the SAME per-step B tiles (dominant cost
// unchanged). Normalized h-tile (34 rows) stays in LDS (Hs); boundary rows
// zeroed ('same' padding); conv2's proven K-loop reads A-frags from Hs.
// Removes: h1 global round trip, conv2 A-stage, one dispatch + gap.
// Arithmetic bitwise-identical to R8 (same MFMA order, same LN reductions).
// K-loop schedule = R8 verbatim (one barrier/step, loads 2 ahead, named
// even/odd reg pairs, NO pragma unroll -- R9 lesson). Blocks 256..511: lr.
// ---------------------------------------------------------------------------
__global__ __launch_bounds__(512)
void fused_conv_lr_kernel(
    const float* __restrict__ x,
    const u16* __restrict__ wp1, const u16* __restrict__ wp2,
    const float* __restrict__ b1, const float* __restrict__ g1,
    const float* __restrict__ e1p,
    const float* __restrict__ b2, const float* __restrict__ g2,
    const float* __restrict__ e2p,
    const float* __restrict__ lw, const float* __restrict__ lb,
    const int* __restrict__ tgt, float* __restrict__ out,
    float* __restrict__ dpo)
{
  __shared__ __align__(16) u16 As66[66 * 264];     // x-stage, 34.8 KB
  __shared__ __align__(16) u16 Hs[34 * 264];       // h-tile,  18.0 KB
  __shared__ __align__(16) u16 Bs[2 * 8192];       // B dbuf,  32.0 KB
  __shared__ float sB1[256], sG1[256], sE1[256];
  __shared__ float sB2[256], sG2[256], sE2[256], sLw[256];
  __shared__ float redS[4][4][16], redQ[4][4][16];
  __shared__ int  sc[512];
  __shared__ int  sidx[256];

  const int blk = (int)blockIdx.x, t = (int)threadIdx.x;
  if (blk >= 256) {                                // ---- LR blocks ----
    lr_body512(blk - 256, t, x, tgt, out, sc, sidx);
    return;
  }

  if (t < 256) {
    sB1[t] = b1[t];  sG1[t] = g1[t];  sE1[t] = e1p[t];
    sB2[t] = b2[t];  sG2[t] = g2[t];  sE2[t] = e2p[t];
    sLw[t] = lw[t];
  }

  const int m0   = blk * 32;
  const int n    = m0 >> 9;
  const int l0   = m0 & 511;
  const int wave = t >> 6, lane = t & 63;
  const int cs   = wave & 3;                        // col-slice 0..3
  const int rha  = wave >> 2;                       // 0..1
  const int wc   = cs * 64;
  const int p    = lane & 15, q = lane >> 4;

  auto LDW = [&](const u16* Wp, int s, uint4 &r0, uint4 &r1) {
    const u16* src = Wp + ((size_t)s << 13);
    r0 = *(const uint4*)(src + (t << 3));
    r1 = *(const uint4*)(src + ((t + 512) << 3));
  };
  auto WRB = [&](int buf, const uint4 &r0, const uint4 &r1) {
    *(uint4*)(Bs + (buf << 13) + (t << 3))         = r0;
    *(uint4*)(Bs + (buf << 13) + ((t + 512) << 3)) = r1;
  };

  // ================= CONV1: 64 rows (groups g = rha, rha+2) =================
  f32x4 acc1[2][4];
  #pragma unroll
  for (int gi = 0; gi < 2; gi++)
    #pragma unroll
    for (int i = 0; i < 4; i++) acc1[gi][i] = (f32x4){0.f, 0.f, 0.f, 0.f};

  auto MF1 = [&](int buf, int s) {
    const u16* bs = Bs + (buf << 13);
    const int tap = s >> 3, dbase = (s & 7) << 5;
    bf16x8 af0 = *(const bf16x8*)(As66 + ((rha << 4)        + p + tap) * 264 + dbase + (q << 3));
    bf16x8 af1 = *(const bf16x8*)(As66 + (((rha + 2) << 4)  + p + tap) * 264 + dbase + (q << 3));
    #pragma unroll
    for (int ct = 0; ct < 4; ct++) {
      bf16x8 bfr = *(const bf16x8*)(bs + ((wc + ct * 16 + p) << 5) + (q << 3));
      acc1[0][ct] = __builtin_amdgcn_mfma_f32_16x16x32_bf16(af0, bfr, acc1[0][ct], 0, 0, 0);
      acc1[1][ct] = __builtin_amdgcn_mfma_f32_16x16x32_bf16(af1, bfr, acc1[1][ct], 0, 0, 0);
    }
  };

  uint4 e0, e1, o0, o1;
  LDW(wp1, 0, e0, e1);
  LDW(wp1, 1, o0, o1);

  // stage x rows m0-17 .. m0+48 (66 rows x 256, bf16), zero-padded
  for (int c = t; c < 66 * 32; c += 512) {
    int row  = c >> 5;
    int col8 = c & 31;
    int l    = l0 - 17 + row;
    uint4 val = make_uint4(0u, 0u, 0u, 0u);
    if ((unsigned)l < 512u) {
      const float* src = x + (((size_t)((n << 9) + l)) << 8) + (col8 << 3);
      float4 v0 = *(const float4*)src;
      float4 v1 = *(const float4*)(src + 4);
      bf16x8 pk = pack8(v0, v1);
      __builtin_memcpy(&val, &pk, 16);
    }
    *(uint4*)(As66 + row * 264 + (col8 << 3)) = val;
  }
  WRB(0, e0, e1);
  __syncthreads();

  for (int s2 = 0; s2 < 24; s2 += 2) {             // R8 schedule
    MF1(0, s2);
    if (s2 + 2 < 24) LDW(wp1, s2 + 2, e0, e1);
    WRB(1, o0, o1);
    __syncthreads();
    MF1(1, s2 + 1);
    if (s2 + 3 < 24) LDW(wp1, s2 + 3, o0, o1);
    if (s2 + 2 < 24) WRB(0, e0, e1);
    __syncthreads();
  }

  // ---- conv1 epilogue: bias + LN per row-group, write Hs (34 rows) ----
  {
    float s0[2][4] = {{0,0,0,0},{0,0,0,0}}, s1[2][4] = {{0,0,0,0},{0,0,0,0}};
    #pragma unroll
    for (int gi = 0; gi < 2; gi++)
      #pragma unroll
      for (int ct = 0; ct < 4; ct++) {
        float bias = sB1[wc + ct * 16 + p];
        #pragma unroll
        for (int j = 0; j < 4; j++) {
          float v = acc1[gi][ct][j] + bias;
          acc1[gi][ct][j] = v;
          s0[gi][j] += v;
          s1[gi][j] += v * v;
        }
      }
    #pragma unroll
    for (int m = 1; m <= 8; m <<= 1)
      #pragma unroll
      for (int gi = 0; gi < 2; gi++)
        #pragma unroll
        for (int j = 0; j < 4; j++) {
          s0[gi][j] += __shfl_xor(s0[gi][j], m);
          s1[gi][j] += __shfl_xor(s1[gi][j], m);
        }
    if (p == 0) {
      #pragma unroll
      for (int gi = 0; gi < 2; gi++) {
        int g = rha + gi * 2;
        #pragma unroll
        for (int j = 0; j < 4; j++) {
          redS[g][cs][q * 4 + j] = s0[gi][j];
          redQ[g][cs][q * 4 + j] = s1[gi][j];
        }
      }
    }
    __syncthreads();
    float mean[2][4], rstd[2][4];
    #pragma unroll
    for (int gi = 0; gi < 2; gi++) {
      int g = rha + gi * 2;
      #pragma unroll
      for (int j = 0; j < 4; j++) {
        int r = q * 4 + j;
        float S = redS[g][0][r] + redS[g][1][r] + redS[g][2][r] + redS[g][3][r];
        float Q = redQ[g][0][r] + redQ[g][1][r] + redQ[g][2][r] + redQ[g][3][r];
        float mu  = S * (1.0f / 256.0f);
        float var = Q * (1.0f / 256.0f) - mu * mu;
        mean[gi][j] = mu;
        rstd[gi][j] = rsqrtf(var + 1e-5f);
      }
    }
    #pragma unroll
    for (int gi = 0; gi < 2; gi++) {
      int g = rha + gi * 2;
      #pragma unroll
      for (int ct = 0; ct < 4; ct++) {
        int c = wc + ct * 16 + p;
        float gg = sG1[c], bb = sE1[c];
        #pragma unroll
        for (int j = 0; j < 4; j++) {
          float v = (acc1[gi][ct][j] - mean[gi][j]) * rstd[gi][j] * gg + bb;
          v = fmaxf(v, 0.0f);
          int hidx = (g << 4) - 15 + q * 4 + j;    // Hs row (global l0-1+hidx)
          if ((unsigned)hidx < 34u)
            Hs[hidx * 264 + c] = f2bf(v);
        }
      }
    }
    __syncthreads();
    // 'same' padding: zero Hs rows whose global l is outside [0,512)
    if (l0 == 0   && t < 132) ((unsigned*)Hs)[t] = 0u;            // row 0
    if (l0 == 480 && t < 132) ((unsigned*)Hs)[33 * 132 + t] = 0u; // row 33
    __syncthreads();
  }

  // ================= CONV2: 32 rows, A from Hs =================
  f32x4 acc2[4];
  #pragma unroll
  for (int i = 0; i < 4; i++) acc2[i] = (f32x4){0.f, 0.f, 0.f, 0.f};

  auto MF2 = [&](int buf, int s) {
    const u16* bs = Bs + (buf << 13);
    const int tap = s >> 3, dbase = (s & 7) << 5;
    bf16x8 af = *(const bf16x8*)(Hs + ((rha << 4) + p + tap) * 264 + dbase + (q << 3));
    #pragma unroll
    for (int ct = 0; ct < 4; ct++) {
      bf16x8 bfr = *(const bf16x8*)(bs + ((wc + ct * 16 + p) << 5) + (q << 3));
      acc2[ct] = __builtin_amdgcn_mfma_f32_16x16x32_bf16(af, bfr, acc2[ct], 0, 0, 0);
    }
  };

  LDW(wp2, 0, e0, e1);
  LDW(wp2, 1, o0, o1);
  WRB(0, e0, e1);
  __syncthreads();

  for (int s2 = 0; s2 < 24; s2 += 2) {             // R8 schedule
    MF2(0, s2);
    if (s2 + 2 < 24) LDW(wp2, s2 + 2, e0, e1);
    WRB(1, o0, o1);
    __syncthreads();
    MF2(1, s2 + 1);
    if (s2 + 3 < 24) LDW(wp2, s2 + 3, o0, o1);
    if (s2 + 2 < 24) WRB(0, e0, e1);
    __syncthreads();
  }

  // ---- conv2 epilogue (proven STAGE-2 math): bias+LN+ReLU, dot lw, dpo ----
  {
    float s0[4] = {0,0,0,0}, s1[4] = {0,0,0,0};
    #pragma unroll
    for (int ct = 0; ct < 4; ct++) {
      float bias = sB2[wc + ct * 16 + p];
      #pragma unroll
      for (int j = 0; j < 4; j++) {
        float v = acc2[ct][j] + bias;
        acc2[ct][j] = v;
        s0[j] += v;
        s1[j] += v * v;
      }
    }
    #pragma unroll
    for (int m = 1; m <= 8; m <<= 1)
      #pragma unroll
      for (int j = 0; j < 4; j++) {
        s0[j] += __shfl_xor(s0[j], m);
        s1[j] += __shfl_xor(s1[j], m);
      }
    if (p == 0) {
      #pragma unroll
      for (int j = 0; j < 4; j++) {
        redS[rha][cs][q * 4 + j] = s0[j];
        redQ[rha][cs][q * 4 + j] = s1[j];
      }
    }
    __syncthreads();
    float mean[4], rstd[4];
    #pragma unroll
    for (int j = 0; j < 4; j++) {
      int r = q * 4 + j;
      float S = redS[rha][0][r] + redS[rha][1][r] + redS[rha][2][r] + redS[rha][3][r];
      float Q = redQ[rha][0][r] + redQ[rha][1][r] + redQ[rha][2][r] + redQ[rha][3][r];
      float mu  = S * (1.0f / 256.0f);
      float var = Q * (1.0f / 256.0f) - mu * mu;
      mean[j] = mu;
      rstd[j] = rsqrtf(var + 1e-5f);
    }
    float ls[4] = {0,0,0,0};
    #pragma unroll
    for (int ct = 0; ct < 4; ct++) {
      int c = wc + ct * 16 + p;
      float gg = sG2[c], bb = sE2[c], ww = sLw[c];
      #pragma unroll
      for (int j = 0; j < 4; j++) {
        float v = (acc2[ct][j] - mean[j]) * rstd[j] * gg + bb;
        v = fmaxf(v, 0.0f);
        ls[j] += v * ww;
      }
    }
    #pragma unroll
    for (int m = 1; m <= 8; m <<= 1)
      #pragma unroll
      for (int j = 0; j < 4; j++) ls[j] += __shfl_xor(ls[j], m);
    __syncthreads();
    if (p == 0) {
      #pragma unroll
      for (int j = 0; j < 4; j++) redS[rha][cs][q * 4 + j] = ls[j];
    }
    __syncthreads();
    if (t < 32) {
      int r2 = t >> 4, ri = t & 15;
      float dv = fmaxf(redS[r2][0][ri] + redS[r2][1][ri] +
                       redS[r2][2][ri] + redS[r2][3][ri] + lb[0], 0.0f);
      dpo[m0 + t] = dv;
    }
  }
}

// ---------------------------------------------------------------------------
// FALLBACK path: exact R8 kernels (proven 121.2us).
// ---------------------------------------------------------------------------
template<int STAGE>
__device__ __forceinline__ void conv_body(
    const int blk, const int t,
    const float* __restrict__ Xf, const u16* __restrict__ Xh,
    const u16* __restrict__ Wp,
    const float* __restrict__ cb,  const float* __restrict__ lgm,
    const float* __restrict__ lbt, const float* __restrict__ lw,
    const float* __restrict__ lb,  u16* __restrict__ Hout,
    float* __restrict__ dpo,
    u16* As, u16* Bs, float* sBias, float* sG, float* sB, float* sLw,
    float (*redS)[4][16], float (*redQ)[4][16])
{
  if (t < 256) {
    sBias[t] = cb[t];
    sG[t]    = lgm[t];
    sB[t]    = lbt[t];
    if (STAGE == 2) sLw[t] = lw[t];
  }

  const int m0   = blk * 32;
  const int n    = m0 >> 9;
  const int l0   = m0 & 511;
  const int wave = t >> 6, lane = t & 63;
  const int cs   = wave & 3;
  const int rh   = wave >> 2;
  const int wc   = cs * 64;
  const int rh16 = rh * 16;
  const int p    = lane & 15, q = lane >> 4;

  f32x4 acc[4];
  #pragma unroll
  for (int i = 0; i < 4; i++) acc[i] = (f32x4){0.f, 0.f, 0.f, 0.f};

  auto LDW = [&](int s, uint4 &r0, uint4 &r1) {
    const u16* src = Wp + ((size_t)s << 13);
    r0 = *(const uint4*)(src + (t << 3));
    r1 = *(const uint4*)(src + ((t + 512) << 3));
  };
  auto WRB = [&](int buf, const uint4 &r0, const uint4 &r1) {
    *(uint4*)(Bs + (buf << 13) + (t << 3))         = r0;
    *(uint4*)(Bs + (buf << 13) + ((t + 512) << 3)) = r1;
  };
  auto MF = [&](int buf, int s) {
    const u16* bs = Bs + (buf << 13);
    const int tap = s >> 3, dbase = (s & 7) << 5;
    bf16x8 af = *(const bf16x8*)(As + (rh16 + p + tap) * 264 + dbase + (q << 3));
    #pragma unroll
    for (int ct = 0; ct < 4; ct++) {
      bf16x8 bfr = *(const bf16x8*)(bs + ((wc + ct * 16 + p) << 5) + (q << 3));
      acc[ct] = __builtin_amdgcn_mfma_f32_16x16x32_bf16(af, bfr, acc[ct], 0, 0, 0);
    }
  };

  uint4 e0, e1, o0, o1;
  LDW(0, e0, e1);
  LDW(1, o0, o1);

  for (int c = t; c < 1088; c += 512) {
    int row  = c >> 5;
    int col8 = c & 31;
    int l    = l0 + row - 1;
    uint4 val;
    if ((unsigned)l < 512u) {
      if (STAGE == 1) {
        const float* src = Xf + (((size_t)((n << 9) + l)) << 8) + (col8 << 3);
        float4 v0 = *(const float4*)src;
        float4 v1 = *(const float4*)(src + 4);
        bf16x8 pk = pack8(v0, v1);
        __builtin_memcpy(&val, &pk, 16);
      } else {
        val = *(const uint4*)(Xh + (((size_t)((n << 9) + l)) << 8) + (col8 << 3));
      }
    } else {
      val = make_uint4(0u, 0u, 0u, 0u);
    }
    *(uint4*)(As + row * 264 + (col8 << 3)) = val;
  }
  WRB(0, e0, e1);
  __syncthreads();

  for (int s2 = 0; s2 < 24; s2 += 2) {
    MF(0, s2);
    if (s2 + 2 < 24) LDW(s2 + 2, e0, e1);
    WRB(1, o0, o1);
    __syncthreads();
    MF(1, s2 + 1);
    if (s2 + 3 < 24) LDW(s2 + 3, o0, o1);
    if (s2 + 2 < 24) WRB(0, e0, e1);
    __syncthreads();
  }

  float s0[4] = {0,0,0,0}, s1[4] = {0,0,0,0};
  #pragma unroll
  for (int ct = 0; ct < 4; ct++) {
    float bias = sBias[wc + ct * 16 + p];
    #pragma unroll
    for (int j = 0; j < 4; j++) {
      float v = acc[ct][j] + bias;
      acc[ct][j] = v;
      s0[j] += v;
      s1[j] += v * v;
    }
  }
  #pragma unroll
  for (int m = 1; m <= 8; m <<= 1) {
    #pragma unroll
    for (int j = 0; j < 4; j++) {
      s0[j] += __shfl_xor(s0[j], m);
      s1[j] += __shfl_xor(s1[j], m);
    }
  }
  if (p == 0) {
    #pragma unroll
    for (int j = 0; j < 4; j++) {
      redS[rh][cs][q * 4 + j] = s0[j];
      redQ[rh][cs][q * 4 + j] = s1[j];
    }
  }
  __syncthreads();
  float mean[4], rstd[4];
  #pragma unroll
  for (int j = 0; j < 4; j++) {
    int r = q * 4 + j;
    float S = redS[rh][0][r] + redS[rh][1][r] + redS[rh][2][r] + redS[rh][3][r];
    float Q = redQ[rh][0][r] + redQ[rh][1][r] + redQ[rh][2][r] + redQ[rh][3][r];
    float mu  = S * (1.0f / 256.0f);
    float var = Q * (1.0f / 256.0f) - mu * mu;
    mean[j] = mu;
    rstd[j] = rsqrtf(var + 1e-5f);
  }

  if (STAGE == 1) {
    #pragma unroll
    for (int ct = 0; ct < 4; ct++) {
      int c = wc + ct * 16 + p;
      float gg = sG[c], bb = sB[c];
      #pragma unroll
      for (int j = 0; j < 4; j++) {
        float v = (acc[ct][j] - mean[j]) * rstd[j] * gg + bb;
        v = fmaxf(v, 0.0f);
        Hout[(size_t)(m0 + rh16 + q * 4 + j) * 256 + c] = f2bf(v);
      }
    }
  } else {
    float ls[4] = {0,0,0,0};
    #pragma unroll
    for (int ct = 0; ct < 4; ct++) {
      int c = wc + ct * 16 + p;
      float gg = sG[c], bb = sB[c], ww = sLw[c];
      #pragma unroll
      for (int j = 0; j < 4; j++) {
        float v = (acc[ct][j] - mean[j]) * rstd[j] * gg + bb;
        v = fmaxf(v, 0.0f);
        ls[j] += v * ww;
      }
    }
    #pragma unroll
    for (int m = 1; m <= 8; m <<= 1) {
      #pragma unroll
      for (int j = 0; j < 4; j++) ls[j] += __shfl_xor(ls[j], m);
    }
    __syncthreads();
    if (p == 0) {
      #pragma unroll
      for (int j = 0; j < 4; j++) redS[rh][cs][q * 4 + j] = ls[j];
    }
    __syncthreads();
    if (t < 32) {
      int r2 = t >> 4, ri = t & 15;
      float dv = fmaxf(redS[r2][0][ri] + redS[r2][1][ri] +
                       redS[r2][2][ri] + redS[r2][3][ri] + lb[0], 0.0f);
      dpo[m0 + t] = dv;
    }
  }
}

template<int STAGE>
__global__ __launch_bounds__(512)
void conv_ln_kernel(const float* __restrict__ Xf, const u16* __restrict__ Xh,
                    const u16* __restrict__ Wp,
                    const float* __restrict__ cb,  const float* __restrict__ lgm,
                    const float* __restrict__ lbt, const float* __restrict__ lw,
                    const float* __restrict__ lb,  u16* __restrict__ Hout,
                    float* __restrict__ dpo)
{
  __shared__ __align__(16) u16 As[34 * 264 + 8];
  __shared__ __align__(16) u16 Bs[2 * 8192];
  __shared__ float sBias[256], sG[256], sB[256], sLw[256];
  __shared__ float redS[2][4][16], redQ[2][4][16];
  conv_body<STAGE>((int)blockIdx.x, (int)threadIdx.x, Xf, Xh, Wp, cb, lgm, lbt,
                   lw, lb, Hout, dpo, As, Bs, sBias, sG, sB, sLw, redS, redQ);
}

__global__ __launch_bounds__(256)
void lr_kernel(const float* __restrict__ X, const int* __restrict__ tgt,
               float* __restrict__ out) {
  __shared__ int c[L_S];
  __shared__ int sidx[TBLK];
  const int t  = threadIdx.x;
  const int n  = blockIdx.x >> 5;
  const int t0 = (blockIdx.x & 31) * TBLK;

  c[t]       = tgt[n * L_S + t];
  c[t + 256] = tgt[n * L_S + t + 256];
  __syncthreads();
  for (int off = 1; off < L_S; off <<= 1) {
    int v0 = (t >= off) ? c[t - off] : 0;
    int i1 = t + 256;
    int v1 = (i1 >= off) ? c[i1 - off] : 0;
    __syncthreads();
    c[t]  += v0;
    c[i1] += v1;
    __syncthreads();
  }
  const int total = c[L_S - 1];
  if (t < TBLK) {
    int tt = t0 + t;
    int lo = 0, hi = L_S;
    while (lo < hi) {
      int mid = (lo + hi) >> 1;
      if (c[mid] <= tt) lo = mid + 1; else hi = mid;
    }
    sidx[t] = (tt < total) ? lo : -1;
  }
  __syncthreads();

  #pragma unroll
  for (int i = 0; i < 32; i++) {
    int u   = t + i * 256;
    int dg  = u & 63;
    int tr  = u >> 6;
    int idx = sidx[tr];
    float4 v = make_float4(0.f, 0.f, 0.f, 0.f);
    if (idx >= 0)
      v = *(const float4*)(X + (((size_t)(n * L_S + idx)) << 8) + dg * 4);
    *(float4*)(out + (((size_t)(n * T_MEL + t0 + tr)) << 8) + dg * 4) = v;
  }
}

// ---------------------------------------------------------------------------
extern "C" void kernel_launch(void* const* d_in, const int* in_sizes, int n_in,
                              void* d_out, int out_size, void* d_ws, size_t ws_size,
                              hipStream_t stream) {
  (void)in_sizes; (void)n_in; (void)out_size;

  const float* x   = (const float*)d_in[0];
  const float* w1  = (const float*)d_in[1];
  const float* b1  = (const float*)d_in[2];
  const float* g1  = (const float*)d_in[3];
  const float* be1 = (const float*)d_in[4];
  const float* w2  = (const float*)d_in[5];
  const float* b2  = (const float*)d_in[6];
  const float* g2  = (const float*)d_in[7];
  const float* be2 = (const float*)d_in[8];
  const float* lw  = (const float*)d_in[9];
  const float* lb  = (const float*)d_in[10];
  const int*   tgt = (const int*)d_in[11];

  float* out = (float*)d_out;
  float* dpo = out + OUT_ELEMS;

  const size_t need_ws = 2 * (size_t)WP_ELEMS * sizeof(u16);   // 768 KB

  if (d_ws != nullptr && ws_size >= need_ws) {
    // 2 dispatches: pack -> fused(conv1+conv2+lr). No h1 at all.
    u16* wp1 = (u16*)d_ws;
    u16* wp2 = wp1 + WP_ELEMS;
    pack_kernel<<<768, 256, 0, stream>>>(w1, w2, wp1, wp2);
    fused_conv_lr_kernel<<<512, 512, 0, stream>>>(
        x, wp1, wp2, b1, g1, be1, b2, g2, be2, lw, lb, tgt, out, dpo);
  } else {
    // Fallback = exact R8 (proven 121.2us): scratch in out, lr LAST.
    u16* h1  = (u16*)d_out;
    u16* wp1 = h1 + H1_ELEMS;
    u16* wp2 = wp1 + WP_ELEMS;
    pack_kernel<<<768, 256, 0, stream>>>(w1, w2, wp1, wp2);
    conv_ln_kernel<1><<<M_TOT / 32, 512, 0, stream>>>(
        x, nullptr, wp1, b1, g1, be1, nullptr, nullptr, h1, nullptr);
    conv_ln_kernel<2><<<M_TOT / 32, 512, 0, stream>>>(
        nullptr, h1, wp2, b2, g2, be2, lw, lb, nullptr, dpo);
    lr_kernel<<<N_B * (T_MEL / TBLK), 256, 0, stream>>>(x, tgt, out);
  }
}